// Round 10
// baseline (147.543 us; speedup 1.0000x reference)
//
#include <hip/hip_runtime.h>
#include <hip/hip_bf16.h>
#include <math.h>

#define NPTS 32768
#define C 64
#define K 16
#define NB2 2048          // sred partial blocks (8192 waves = 8/SIMD)
#define NB2R 64           // after sred2 hierarchical reduce
#define NTAB 512          // table cells for the per-k PWL function F_kc(t)
#define XCH 8             // xvec n-chunks
#define BN_INV 0.99999500003749968f   // 1/sqrt(1+1e-5)

__device__ __forceinline__ float safediv_n2n(float a, float b) {
    float q = a / b;
    if (isnan(q)) return 0.0f;
    if (isinf(q)) return copysignf(3.402823466e38f, q);
    return q;
}

__device__ __forceinline__ float bf16f(ushort u) {
    return __uint_as_float((unsigned)u << 16);
}

// ---------------------------------------------------------------------------
// K1 (prep): grid (512, 3), block 256. Proven single-accumulator shape.
// dir 0: y tile -> y_k (bf16).  dir 1: xuni + xyz pack.  dir 2: y tile -> y_v.
// ---------------------------------------------------------------------------
__global__ __launch_bounds__(256) void prep_kernel(
    const float* __restrict__ x, const float* __restrict__ y,
    const float* __restrict__ y_xyz,
    const float* __restrict__ Wk, const float* __restrict__ bk,
    const float* __restrict__ Wv, const float* __restrict__ bv,
    const float* __restrict__ Wu, const float* __restrict__ bu,
    const float* __restrict__ gu, const float* __restrict__ bnu,
    __hip_bfloat16* __restrict__ ykb, __hip_bfloat16* __restrict__ yvb,
    float* __restrict__ xu, float4* __restrict__ pk)
{
    const int dir  = blockIdx.y;
    const int lane = threadIdx.x & 63;
    const int wave = threadIdx.x >> 6;

    if (dir == 1) {
        const float wul = Wu[lane];
        const float bnscale = gu[0] * BN_INV;
        const float bu0 = bu[0], bnu0 = bnu[0];
        #pragma unroll 4
        for (int i = 0; i < 16; ++i) {
            const int m = blockIdx.x * 64 + wave * 16 + i;
            float v = x[m * 64 + lane] * wul;
            #pragma unroll
            for (int off = 32; off > 0; off >>= 1) v += __shfl_xor(v, off, 64);
            if (lane == 0) {
                float u = (v + bu0) * bnscale + bnu0;
                xu[m] = fmaxf(u, 0.0f);
            }
        }
        if (wave == 0) {
            const int p = blockIdx.x * 64 + lane;
            pk[p] = make_float4(y_xyz[p], y_xyz[NPTS + p], y_xyz[2 * NPTS + p], 0.0f);
        }
        return;
    }

    const float* __restrict__ W    = (dir == 0) ? Wk : Wv;
    const float* __restrict__ bias = (dir == 0) ? bk : bv;
    __hip_bfloat16* __restrict__ dst = (dir == 0) ? ykb : yvb;

    const int n0 = blockIdx.x * 64;
    __shared__ float hs[C][C];          // 16 KB

    #pragma unroll
    for (int i = 0; i < 16; ++i) {
        const int c = i * 4 + wave;
        hs[c][lane] = y[(size_t)c * NPTS + n0 + lane];
    }
    __syncthreads();

    const int p0 = wave * 16;
    float acc[16];
    const float b = bias[lane];
    #pragma unroll
    for (int i = 0; i < 16; ++i) acc[i] = b;

    #pragma unroll
    for (int c = 0; c < C; ++c) {
        const float wcl = W[c * C + lane];
        float va[16];
        ((float4*)va)[0] = *(const float4*)&hs[c][p0];
        ((float4*)va)[1] = *(const float4*)&hs[c][p0 + 4];
        ((float4*)va)[2] = *(const float4*)&hs[c][p0 + 8];
        ((float4*)va)[3] = *(const float4*)&hs[c][p0 + 12];
        #pragma unroll
        for (int i = 0; i < 16; ++i) acc[i] = fmaf(va[i], wcl, acc[i]);
    }

    #pragma unroll
    for (int i = 0; i < 16; ++i)
        dst[(size_t)(n0 + p0 + i) * C + lane] = __float2bfloat16(acc[i]);
}

// ---------------------------------------------------------------------------
// K2 (sredx): blocks [0,NB2): partial G[c][k] = sum_n y_k[idx[n,k]][c]*xu[n]
//            blocks [NB2, NB2+520): xvec partials (j = b/XCH, chunk = b%XCH)
// ---------------------------------------------------------------------------
__global__ __launch_bounds__(256) void sredx_kernel(
    const __hip_bfloat16* __restrict__ ykb,
    const float* __restrict__ x,
    const float* __restrict__ xu, const int* __restrict__ idx,
    float* __restrict__ partG, float* __restrict__ xvecp)
{
    __shared__ float red[4][K][C];      // 16 KB (sred part)
    __shared__ float xred[256];         // 1 KB  (xvec part)

    if (blockIdx.x >= NB2) {
        // ---- xvec partials ----
        const int b  = blockIdx.x - NB2;
        const int j  = b / XCH;          // 0..64
        const int ch = b % XCH;          // 0..7
        const int t  = threadIdx.x;
        const int nb = NPTS / XCH;       // 4096
        const int n0 = ch * nb;
        float s = 0.0f;
        if (j < C) {
            const float* __restrict__ row = x + (size_t)j * NPTS + n0;
            const float* __restrict__ xr  = xu + n0;
            for (int n = t; n < nb; n += 256) s = fmaf(row[n], xr[n], s);
        } else {
            const float* __restrict__ xr = xu + n0;
            for (int n = t; n < nb; n += 256) s += xr[n];
        }
        xred[t] = s;
        __syncthreads();
        #pragma unroll
        for (int off = 128; off > 0; off >>= 1) {
            if (t < off) xred[t] += xred[t + off];
            __syncthreads();
        }
        if (t == 0) xvecp[j * XCH + ch] = xred[0];
        return;
    }

    const int lane = threadIdx.x & 63;
    const int wv = __builtin_amdgcn_readfirstlane(threadIdx.x >> 6);
    const int gw = blockIdx.x * 4 + wv;
    const int nwv = NB2 * 4;
    const ushort* __restrict__ yku = (const ushort*)ykb;

    float g[K];
    #pragma unroll
    for (int k = 0; k < K; ++k) g[k] = 0.0f;

    for (int n = gw; n < NPTS; n += nwv) {
        const float xuv = xu[n];                       // uniform (s_load)
        if (xuv != 0.0f) {                             // uniform branch
            const int4* ir = (const int4*)(idx + (size_t)n * K);
            const int4 i0 = ir[0], i1 = ir[1], i2 = ir[2], i3 = ir[3];
            int ids[K] = { i0.x, i0.y, i0.z, i0.w, i1.x, i1.y, i1.z, i1.w,
                           i2.x, i2.y, i2.z, i2.w, i3.x, i3.y, i3.z, i3.w };
            #pragma unroll
            for (int k = 0; k < K; ++k) {
                const float ykv = bf16f(yku[(size_t)ids[k] * C + lane]);
                g[k] = fmaf(ykv, xuv, g[k]);
            }
        }
    }

    #pragma unroll
    for (int k = 0; k < K; ++k) red[wv][k][lane] = g[k];
    __syncthreads();
    if (wv == 0) {
        #pragma unroll
        for (int k = 0; k < K; ++k) {
            float s = red[0][k][lane] + red[1][k][lane] + red[2][k][lane] + red[3][k][lane];
            partG[blockIdx.x * (K * C) + k * C + lane] = s;
        }
    }
}

// ---------------------------------------------------------------------------
// K2a: hierarchical reduce NB2 -> 64 partials (deterministic)
// ---------------------------------------------------------------------------
__global__ __launch_bounds__(1024) void sred2_kernel(
    const float* __restrict__ partG, float* __restrict__ part2)
{
    const int j = blockIdx.x;       // 0..63
    const int t = threadIdx.x;      // 0..1023
    float s = 0.0f;
    #pragma unroll 8
    for (int i = 0; i < NB2 / NB2R; ++i)
        s += partG[(size_t)(j + NB2R * i) * (K * C) + t];
    part2[(size_t)j * (K * C) + t] = s;
}

// ---------------------------------------------------------------------------
// K2b: S[k][c] = (reduced G) - T1[c],
//   T1[c] = sum_j Wq[j][c]*xvec[j] + bq[c]*xvec[64]    (x_q eliminated)
// then softmax over k -> wd[c][k], awdT[k][c] = a_p[k]*wd
// ---------------------------------------------------------------------------
__global__ __launch_bounds__(1024) void wd_kernel(
    const float* __restrict__ part2, const float* __restrict__ xvecp,
    const float* __restrict__ Wq, const float* __restrict__ bq,
    const float* __restrict__ a_p,
    float* __restrict__ wd, float* __restrict__ awdT)
{
    __shared__ float S[K][C];
    __shared__ float xv[C + 1];
    __shared__ float T1s[C];
    const int t = threadIdx.x;          // t = k*64 + c
    const int c = t & 63;

    if (t < C + 1) {
        float s = 0.0f;
        #pragma unroll
        for (int ch = 0; ch < XCH; ++ch) s += xvecp[t * XCH + ch];
        xv[t] = s;
    }
    float s = 0.0f;
    #pragma unroll 8
    for (int b = 0; b < NB2R; ++b) s += part2[b * (K * C) + t];
    __syncthreads();

    if (t < C) {
        float t1 = bq[t] * xv[C];
        #pragma unroll 8
        for (int j = 0; j < C; ++j) t1 = fmaf(Wq[j * C + t], xv[j], t1);
        T1s[t] = t1;
    }
    __syncthreads();

    S[0][t] = s - T1s[c];
    __syncthreads();

    if (t < C) {
        float v[K];
        float m = -3.402823466e38f;
        #pragma unroll
        for (int k = 0; k < K; ++k) { v[k] = S[k][t]; m = fmaxf(m, v[k]); }
        float sum = 0.0f;
        #pragma unroll
        for (int k = 0; k < K; ++k) { v[k] = expf(v[k] - m); sum += v[k]; }
        const float r = 1.0f / sum;
        #pragma unroll
        for (int k = 0; k < K; ++k) {
            const float wv = v[k] * r;
            wd[t * K + k] = wv;
            awdT[k * C + t] = a_p[k] * wv;
        }
    }
}

// ---------------------------------------------------------------------------
// K3 (wetab): blocks [0,128): w_e softmax rows.  blocks [128,260): table.
// Both depend only on wd/awdT; independent of each other.
// ---------------------------------------------------------------------------
__global__ __launch_bounds__(256) void wetab_kernel(
    const float* __restrict__ y, const float* __restrict__ wd,
    const float* __restrict__ awdT, const float* __restrict__ b_p,
    const float* __restrict__ Ww1, const float* __restrict__ bw1,
    const float* __restrict__ Ww2, const float* __restrict__ bw2,
    const float* __restrict__ gw1, const float* __restrict__ bw1b,
    const float* __restrict__ gw2, const float* __restrict__ bw2b,
    float* __restrict__ we, float* __restrict__ tab)
{
    __shared__ float smem[4 * 16 * C];      // 16 KB, dual-purpose
    const int lane = threadIdx.x & 63;
    const int wave = threadIdx.x >> 6;

    if (blockIdx.x < 128) {
        // ---- we: w_e[n][k] = softmax_k( sum_c y[c][n] * wd[c][k] ) ----
        float* wds = smem;                   // [C][K]
        for (int i = threadIdx.x; i < C * K; i += 256) wds[i] = wd[i];
        __syncthreads();

        const int n = (blockIdx.x * 4 + wave) * 64 + lane;
        float L[K];
        #pragma unroll
        for (int k = 0; k < K; ++k) L[k] = 0.0f;
        for (int c = 0; c < C; ++c) {
            const float yv = y[c * NPTS + n];
            float wa[K];
            ((float4*)wa)[0] = ((const float4*)&wds[c * K])[0];
            ((float4*)wa)[1] = ((const float4*)&wds[c * K])[1];
            ((float4*)wa)[2] = ((const float4*)&wds[c * K])[2];
            ((float4*)wa)[3] = ((const float4*)&wds[c * K])[3];
            #pragma unroll
            for (int k = 0; k < K; ++k) L[k] = fmaf(yv, wa[k], L[k]);
        }
        float m = L[0];
        #pragma unroll
        for (int k = 1; k < K; ++k) m = fmaxf(m, L[k]);
        float sum = 0.0f;
        #pragma unroll
        for (int k = 0; k < K; ++k) { L[k] = expf(L[k] - m); sum += L[k]; }
        const float r = 1.0f / sum;
        float* dst = we + (size_t)n * K;
        ((float4*)dst)[0] = make_float4(L[0]*r, L[1]*r, L[2]*r, L[3]*r);
        ((float4*)dst)[1] = make_float4(L[4]*r, L[5]*r, L[6]*r, L[7]*r);
        ((float4*)dst)[2] = make_float4(L[8]*r, L[9]*r, L[10]*r, L[11]*r);
        ((float4*)dst)[3] = make_float4(L[12]*r, L[13]*r, L[14]*r, L[15]*r);
        return;
    }

    // ---- tab: wave gwv handles (i0 = (gwv%33)*16, k = gwv/33) ----
    const int gwv = (blockIdx.x - 128) * 4 + wave;      // 0..527
    const int k  = gwv / 33;
    const int i0 = (gwv % 33) * 16;
    float* hs = smem + wave * 16 * C;    // per-wave [16][C]

    const float aw = awdT[k * C + lane];
    const float bp = b_p[k * C + lane];
    const float gs1 = gw1[lane] * BN_INV, bb1 = bw1b[lane], bw1c = bw1[lane];
    const float gs2 = gw2[lane] * BN_INV, bb2 = bw2b[lane], bw2c = bw2[lane];

    float w1c[C], w2c[C];
    #pragma unroll
    for (int c = 0; c < C; ++c) { w1c[c] = Ww1[c * C + lane]; w2c[c] = Ww2[c * C + lane]; }

    #pragma unroll
    for (int r = 0; r < 16; ++r) {
        const float t = (float)(i0 + r) * (1.0f / NTAB);
        const float wv = fmaf(bp, t, aw);
        hs[r * C + lane] = fmaxf(fmaf(wv, gs1, bb1), 0.0f);
    }
    __syncthreads();

    float o[16];
    #pragma unroll
    for (int r = 0; r < 16; ++r) o[r] = bw1c;
    #pragma unroll
    for (int c4 = 0; c4 < 16; ++c4) {
        #pragma unroll
        for (int r = 0; r < 16; ++r) {
            const float4 hv = *(const float4*)&hs[r * C + c4 * 4];
            o[r] = fmaf(hv.x, w1c[c4 * 4 + 0], o[r]);
            o[r] = fmaf(hv.y, w1c[c4 * 4 + 1], o[r]);
            o[r] = fmaf(hv.z, w1c[c4 * 4 + 2], o[r]);
            o[r] = fmaf(hv.w, w1c[c4 * 4 + 3], o[r]);
        }
    }
    __syncthreads();
    #pragma unroll
    for (int r = 0; r < 16; ++r)
        hs[r * C + lane] = fmaxf(fmaf(o[r], gs2, bb2), 0.0f);
    __syncthreads();
    #pragma unroll
    for (int r = 0; r < 16; ++r) o[r] = bw2c;
    #pragma unroll
    for (int c4 = 0; c4 < 16; ++c4) {
        #pragma unroll
        for (int r = 0; r < 16; ++r) {
            const float4 hv = *(const float4*)&hs[r * C + c4 * 4];
            o[r] = fmaf(hv.x, w2c[c4 * 4 + 0], o[r]);
            o[r] = fmaf(hv.y, w2c[c4 * 4 + 1], o[r]);
            o[r] = fmaf(hv.z, w2c[c4 * 4 + 2], o[r]);
            o[r] = fmaf(hv.w, w2c[c4 * 4 + 3], o[r]);
        }
    }
    #pragma unroll
    for (int r = 0; r < 16; ++r) {
        const int i = i0 + r;
        if (i <= NTAB) tab[(k * (NTAB + 1) + i) * C + lane] = o[r];
    }
}

// ---------------------------------------------------------------------------
// K4 (hot): ONE point per wave (grid 8192 x 4 waves), lane = channel c.
// ---------------------------------------------------------------------------
__global__ __launch_bounds__(256, 5) void main4_kernel(
    const int* __restrict__ idx, const float4* __restrict__ pk,
    const __hip_bfloat16* __restrict__ yvb, const float* __restrict__ we,
    const float* __restrict__ tab, const float* __restrict__ d_p,
    const float* __restrict__ Wa1, const float* __restrict__ ba1,
    const float* __restrict__ ga, const float* __restrict__ bna,
    const float* __restrict__ Wa2, const float* __restrict__ ba2,
    const float* __restrict__ Wp1, const float* __restrict__ bp1,
    const float* __restrict__ gp, const float* __restrict__ bnp,
    const float* __restrict__ Wp2, const float* __restrict__ bp2,
    float* __restrict__ out)
{
    const int lane = threadIdx.x & 63;
    const int wv = __builtin_amdgcn_readfirstlane(threadIdx.x >> 6);
    const int n = blockIdx.x * 4 + wv;                 // uniform point id

    __shared__ float geo[4][K][8];
    __shared__ float prm[36];

    if (threadIdx.x < 36) {
        const int t = threadIdx.x;
        float v;
        if (t < 9)       v = Wa1[t];
        else if (t < 12) v = ba1[t - 9];
        else if (t < 21) v = Wp1[t - 12];
        else if (t < 24) v = bp1[t - 21];
        else if (t < 27) v = ga[t - 24];
        else if (t < 30) v = bna[t - 27];
        else if (t < 33) v = gp[t - 30];
        else             v = bnp[t - 33];
        prm[t] = v;
    }
    __syncthreads();

    // ---- uniform loads (scalar path) ----
    const int4* ir = (const int4*)(idx + (size_t)n * K);
    const int4 i0 = ir[0], i1 = ir[1], i2 = ir[2], i3 = ir[3];
    const int ids[K] = { i0.x, i0.y, i0.z, i0.w, i1.x, i1.y, i1.z, i1.w,
                         i2.x, i2.y, i2.z, i2.w, i3.x, i3.y, i3.z, i3.w };
    const float4 self = pk[n];
    const float4 wv0 = ((const float4*)(we + (size_t)n * K))[0];
    const float4 wv1 = ((const float4*)(we + (size_t)n * K))[1];
    const float4 wv2 = ((const float4*)(we + (size_t)n * K))[2];
    const float4 wv3 = ((const float4*)(we + (size_t)n * K))[3];
    const float wearr[K] = { wv0.x, wv0.y, wv0.z, wv0.w, wv1.x, wv1.y, wv1.z, wv1.w,
                             wv2.x, wv2.y, wv2.z, wv2.w, wv3.x, wv3.y, wv3.z, wv3.w };

    // ---- per-lane gathers: yv rows (saddr + lane*2) ----
    const ushort* __restrict__ yvu_base = (const ushort*)yvb;
    ushort yvu[K];
    #pragma unroll
    for (int k = 0; k < K; ++k)
        yvu[k] = yvu_base[(size_t)ids[k] * C + lane];

    // ---- geometry (lanes compute k = lane&15; lanes<16 write LDS) ----
    {
        const int idv = (idx + (size_t)n * K)[lane & 15];   // per-lane
        const float4 nb = pk[idv];
        const float px = nb.x - self.x;
        const float py = nb.y - self.y;
        const float pz = nb.z - self.z;
        const float ed  = sqrtf(px * px + py * py + pz * pz);
        const float exy = sqrtf(px * px + py * py);
        const float cose = safediv_n2n(exy, ed);
        const float cosa = safediv_n2n(py, exy);
        float gv[6];
        #pragma unroll
        for (int d = 0; d < 3; ++d) {
            const float a = ed * prm[d] + cosa * prm[3 + d] + cose * prm[6 + d] + prm[9 + d];
            gv[d] = fmaxf(a * (prm[24 + d] * BN_INV) + prm[27 + d], 0.0f);
            const float p = px * prm[12 + d] + py * prm[15 + d] + pz * prm[18 + d] + prm[21 + d];
            gv[3 + d] = fmaxf(p * (prm[30 + d] * BN_INV) + prm[33 + d], 0.0f);
        }
        if (lane < K) {
            float* g = &geo[wv][lane][0];
            g[1] = gv[0]; g[2] = gv[1]; g[3] = gv[2];
            g[4] = gv[3]; g[5] = gv[4]; g[6] = gv[5];
        }
    }

    // ---- w2[k] via table lerp, two batches of 8 (register diet) ----
    float w2[K];
    #pragma unroll
    for (int h = 0; h < 2; ++h) {
        float tv0[8], tv1[8], fr[8];
        #pragma unroll
        for (int j = 0; j < 8; ++j) {
            const int k = h * 8 + j;
            const float u = wearr[k] * (float)NTAB;
            int ic = (int)u;
            ic = (ic < 0) ? 0 : (ic > NTAB - 1 ? NTAB - 1 : ic);
            fr[j] = u - (float)ic;
            const float* tp = tab + ((size_t)(k * (NTAB + 1) + ic) << 6) + lane;
            tv0[j] = tp[0];
            tv1[j] = tp[C];
        }
        #pragma unroll
        for (int j = 0; j < 8; ++j)
            w2[h * 8 + j] = fmaf(fr[j], tv1[j] - tv0[j], tv0[j]);
    }

    // ---- softmax over k ----
    float m = w2[0];
    #pragma unroll
    for (int k = 1; k < K; ++k) m = fmaxf(m, w2[k]);
    float sum = 0.0f;
    #pragma unroll
    for (int k = 0; k < K; ++k) { w2[k] = __expf(w2[k] - m); sum += w2[k]; }
    const float r = 1.0f / sum;

    // ---- per-lane params ----
    const float ba2c = ba2[lane], bp2c = bp2[lane];
    float wa2c[3], wp2c[3];
    #pragma unroll
    for (int d = 0; d < 3; ++d) { wa2c[d] = Wa2[d * C + lane]; wp2c[d] = Wp2[d * C + lane]; }

    // ---- epilogue: out = sum_k (y_v_gather + p_r) * w ----
    float acc = 0.0f;
    #pragma unroll
    for (int k = 0; k < K; ++k) {
        const float4 g0 = *(const float4*)&geo[wv][k][0];
        const float4 g1 = *(const float4*)&geo[wv][k][4];
        const float afc = fmaf(g0.y, wa2c[0], fmaf(g0.z, wa2c[1], fmaf(g0.w, wa2c[2], ba2c)));
        float prc = fmaf(g1.x, wp2c[0], fmaf(g1.y, wp2c[1], fmaf(g1.z, wp2c[2], bp2c)));
        prc = fmaf(d_p[k * C + lane], afc, prc);
        acc = fmaf(bf16f(yvu[k]) + prc, w2[k] * r, acc);
    }
    out[(size_t)n * C + lane] = acc;
}

// ---------------------------------------------------------------------------
extern "C" void kernel_launch(void* const* d_in, const int* in_sizes, int n_in,
                              void* d_out, int out_size, void* d_ws, size_t ws_size,
                              hipStream_t stream)
{
    (void)in_sizes; (void)n_in; (void)out_size; (void)ws_size;
    const float* x     = (const float*)d_in[0];
    const float* y     = (const float*)d_in[1];
    const float* y_xyz = (const float*)d_in[2];
    const int*   idx   = (const int*)d_in[3];
    const float* Wq = (const float*)d_in[4];  const float* bq = (const float*)d_in[5];
    const float* Wk = (const float*)d_in[6];  const float* bk = (const float*)d_in[7];
    const float* Wv = (const float*)d_in[8];  const float* bv = (const float*)d_in[9];
    const float* Wu = (const float*)d_in[10]; const float* bu = (const float*)d_in[11];
    const float* gu = (const float*)d_in[12]; const float* bnu = (const float*)d_in[13];
    const float* Wp1 = (const float*)d_in[14]; const float* bp1 = (const float*)d_in[15];
    const float* gp  = (const float*)d_in[16]; const float* bnp = (const float*)d_in[17];
    const float* Wp2 = (const float*)d_in[18]; const float* bp2 = (const float*)d_in[19];
    const float* Wa1 = (const float*)d_in[20]; const float* ba1 = (const float*)d_in[21];
    const float* ga  = (const float*)d_in[22]; const float* bna = (const float*)d_in[23];
    const float* Wa2 = (const float*)d_in[24]; const float* ba2 = (const float*)d_in[25];
    const float* gw1 = (const float*)d_in[26]; const float* bw1b = (const float*)d_in[27];
    const float* Ww1 = (const float*)d_in[28]; const float* bw1 = (const float*)d_in[29];
    const float* gw2 = (const float*)d_in[30]; const float* bw2b = (const float*)d_in[31];
    const float* Ww2 = (const float*)d_in[32]; const float* bw2 = (const float*)d_in[33];
    const float* a_p = (const float*)d_in[34];
    const float* b_p = (const float*)d_in[35];
    const float* d_p = (const float*)d_in[36];
    float* out = (float*)d_out;

    float* ws = (float*)d_ws;
    // layout (float offsets), compacted:
    float* we    = ws;                                   // 524288
    float* tab   = ws + 524288;                          // 525312 -> 1049600
    __hip_bfloat16* ykb = (__hip_bfloat16*)(ws + 1049600);   // 4MB -> +1048576
    __hip_bfloat16* yvb = (__hip_bfloat16*)(ws + 2098176);   // 4MB -> +1048576
    float4* pk   = (float4*)(ws + 3146752);              // 131072 -> 3277824
    float* xu    = ws + 3277824;                         // 32768 -> 3310592
    float* partG = ws + 3310592;                         // 2048*1024 -> 5407744
    float* part2 = ws + 5407744;                         // 65536 -> 5473280
    float* wd    = ws + 5473280;                         // 1024
    float* awdT  = ws + 5474304;                         // 1024
    float* xvecp = ws + 5475328;                         // 520

    prep_kernel<<<dim3(NPTS / 64, 3), 256, 0, stream>>>(
        x, y, y_xyz, Wk, bk, Wv, bv, Wu, bu, gu, bnu, ykb, yvb, xu, pk);
    sredx_kernel<<<NB2 + (C + 1) * XCH, 256, 0, stream>>>(
        ykb, x, xu, idx, partG, xvecp);
    sred2_kernel<<<NB2R, 1024, 0, stream>>>(partG, part2);
    wd_kernel<<<1, 1024, 0, stream>>>(part2, xvecp, Wq, bq, a_p, wd, awdT);
    wetab_kernel<<<128 + 132, 256, 0, stream>>>(
        y, wd, awdT, b_p, Ww1, bw1, Ww2, bw2, gw1, bw1b, gw2, bw2b, we, tab);
    main4_kernel<<<NPTS / 4, 256, 0, stream>>>(idx, pk, yvb, we, tab, d_p,
        Wa1, ba1, ga, bna, Wa2, ba2, Wp1, bp1, gp, bnp, Wp2, bp2, out);
}

// Round 11
// 100.895 us; speedup vs baseline: 1.4623x; 1.4623x over previous
//
#include <hip/hip_runtime.h>
#include <hip/hip_bf16.h>
#include <math.h>

#define NPTS 32768
#define C 64
#define K 16
#define NB2 2048          // sred partial blocks (8192 waves = 8/SIMD)
#define NB2R 64           // after sred2 hierarchical reduce
#define NTAB 512          // table cells for the per-k PWL function F_kc(t)
#define XCH 8             // xvec n-chunks
#define BN_INV 0.99999500003749968f   // 1/sqrt(1+1e-5)

__device__ __forceinline__ float safediv_n2n(float a, float b) {
    float q = a / b;
    if (isnan(q)) return 0.0f;
    if (isinf(q)) return copysignf(3.402823466e38f, q);
    return q;
}

__device__ __forceinline__ float bf16f(ushort u) {
    return __uint_as_float((unsigned)u << 16);
}

// ---------------------------------------------------------------------------
// K1 (prep): grid (512, 3), block 256. Proven single-accumulator shape.
// dir 0: y tile -> y_k (bf16).  dir 1: xuni + xyz pack.  dir 2: y tile -> y_v.
// ---------------------------------------------------------------------------
__global__ __launch_bounds__(256) void prep_kernel(
    const float* __restrict__ x, const float* __restrict__ y,
    const float* __restrict__ y_xyz,
    const float* __restrict__ Wk, const float* __restrict__ bk,
    const float* __restrict__ Wv, const float* __restrict__ bv,
    const float* __restrict__ Wu, const float* __restrict__ bu,
    const float* __restrict__ gu, const float* __restrict__ bnu,
    __hip_bfloat16* __restrict__ ykb, __hip_bfloat16* __restrict__ yvb,
    float* __restrict__ xu, float4* __restrict__ pk)
{
    const int dir  = blockIdx.y;
    const int lane = threadIdx.x & 63;
    const int wave = threadIdx.x >> 6;

    if (dir == 1) {
        const float wul = Wu[lane];
        const float bnscale = gu[0] * BN_INV;
        const float bu0 = bu[0], bnu0 = bnu[0];
        #pragma unroll 4
        for (int i = 0; i < 16; ++i) {
            const int m = blockIdx.x * 64 + wave * 16 + i;
            float v = x[m * 64 + lane] * wul;
            #pragma unroll
            for (int off = 32; off > 0; off >>= 1) v += __shfl_xor(v, off, 64);
            if (lane == 0) {
                float u = (v + bu0) * bnscale + bnu0;
                xu[m] = fmaxf(u, 0.0f);
            }
        }
        if (wave == 0) {
            const int p = blockIdx.x * 64 + lane;
            pk[p] = make_float4(y_xyz[p], y_xyz[NPTS + p], y_xyz[2 * NPTS + p], 0.0f);
        }
        return;
    }

    const float* __restrict__ W    = (dir == 0) ? Wk : Wv;
    const float* __restrict__ bias = (dir == 0) ? bk : bv;
    __hip_bfloat16* __restrict__ dst = (dir == 0) ? ykb : yvb;

    const int n0 = blockIdx.x * 64;
    __shared__ float hs[C][C];          // 16 KB

    #pragma unroll
    for (int i = 0; i < 16; ++i) {
        const int c = i * 4 + wave;
        hs[c][lane] = y[(size_t)c * NPTS + n0 + lane];
    }
    __syncthreads();

    const int p0 = wave * 16;
    float acc[16];
    const float b = bias[lane];
    #pragma unroll
    for (int i = 0; i < 16; ++i) acc[i] = b;

    #pragma unroll
    for (int c = 0; c < C; ++c) {
        const float wcl = W[c * C + lane];
        float va[16];
        ((float4*)va)[0] = *(const float4*)&hs[c][p0];
        ((float4*)va)[1] = *(const float4*)&hs[c][p0 + 4];
        ((float4*)va)[2] = *(const float4*)&hs[c][p0 + 8];
        ((float4*)va)[3] = *(const float4*)&hs[c][p0 + 12];
        #pragma unroll
        for (int i = 0; i < 16; ++i) acc[i] = fmaf(va[i], wcl, acc[i]);
    }

    #pragma unroll
    for (int i = 0; i < 16; ++i)
        dst[(size_t)(n0 + p0 + i) * C + lane] = __float2bfloat16(acc[i]);
}

// ---------------------------------------------------------------------------
// K2 (sredx): blocks [0,NB2): partial G[c][k] = sum_n y_k[idx[n,k]][c]*xu[n]
//            blocks [NB2, NB2+520): xvec partials (j = b/XCH, chunk = b%XCH)
// ---------------------------------------------------------------------------
__global__ __launch_bounds__(256) void sredx_kernel(
    const __hip_bfloat16* __restrict__ ykb,
    const float* __restrict__ x,
    const float* __restrict__ xu, const int* __restrict__ idx,
    float* __restrict__ partG, float* __restrict__ xvecp)
{
    __shared__ float red[4][K][C];      // 16 KB (sred part)
    __shared__ float xred[256];         // 1 KB  (xvec part)

    if (blockIdx.x >= NB2) {
        // ---- xvec partials ----
        const int b  = blockIdx.x - NB2;
        const int j  = b / XCH;          // 0..64
        const int ch = b % XCH;          // 0..7
        const int t  = threadIdx.x;
        const int nb = NPTS / XCH;       // 4096
        const int n0 = ch * nb;
        float s = 0.0f;
        if (j < C) {
            const float* __restrict__ row = x + (size_t)j * NPTS + n0;
            const float* __restrict__ xr  = xu + n0;
            for (int n = t; n < nb; n += 256) s = fmaf(row[n], xr[n], s);
        } else {
            const float* __restrict__ xr = xu + n0;
            for (int n = t; n < nb; n += 256) s += xr[n];
        }
        xred[t] = s;
        __syncthreads();
        #pragma unroll
        for (int off = 128; off > 0; off >>= 1) {
            if (t < off) xred[t] += xred[t + off];
            __syncthreads();
        }
        if (t == 0) xvecp[j * XCH + ch] = xred[0];
        return;
    }

    const int lane = threadIdx.x & 63;
    const int wv = __builtin_amdgcn_readfirstlane(threadIdx.x >> 6);
    const int gw = blockIdx.x * 4 + wv;
    const int nwv = NB2 * 4;
    const ushort* __restrict__ yku = (const ushort*)ykb;

    float g[K];
    #pragma unroll
    for (int k = 0; k < K; ++k) g[k] = 0.0f;

    for (int n = gw; n < NPTS; n += nwv) {
        const float xuv = xu[n];                       // uniform (s_load)
        if (xuv != 0.0f) {                             // uniform branch
            const int4* ir = (const int4*)(idx + (size_t)n * K);
            const int4 i0 = ir[0], i1 = ir[1], i2 = ir[2], i3 = ir[3];
            int ids[K] = { i0.x, i0.y, i0.z, i0.w, i1.x, i1.y, i1.z, i1.w,
                           i2.x, i2.y, i2.z, i2.w, i3.x, i3.y, i3.z, i3.w };
            #pragma unroll
            for (int k = 0; k < K; ++k) {
                const float ykv = bf16f(yku[(size_t)ids[k] * C + lane]);
                g[k] = fmaf(ykv, xuv, g[k]);
            }
        }
    }

    #pragma unroll
    for (int k = 0; k < K; ++k) red[wv][k][lane] = g[k];
    __syncthreads();
    if (wv == 0) {
        #pragma unroll
        for (int k = 0; k < K; ++k) {
            float s = red[0][k][lane] + red[1][k][lane] + red[2][k][lane] + red[3][k][lane];
            partG[blockIdx.x * (K * C) + k * C + lane] = s;
        }
    }
}

// ---------------------------------------------------------------------------
// K2a: hierarchical reduce NB2 -> 64 partials (deterministic)
// ---------------------------------------------------------------------------
__global__ __launch_bounds__(1024) void sred2_kernel(
    const float* __restrict__ partG, float* __restrict__ part2)
{
    const int j = blockIdx.x;       // 0..63
    const int t = threadIdx.x;      // 0..1023
    float s = 0.0f;
    #pragma unroll 8
    for (int i = 0; i < NB2 / NB2R; ++i)
        s += partG[(size_t)(j + NB2R * i) * (K * C) + t];
    part2[(size_t)j * (K * C) + t] = s;
}

// ---------------------------------------------------------------------------
// K2b: S[k][c] = (reduced G) - T1[c],
//   T1[c] = sum_j Wq[j][c]*xvec[j] + bq[c]*xvec[64]    (x_q eliminated)
// then softmax over k -> wd[c][k], awdT[k][c] = a_p[k]*wd
// ---------------------------------------------------------------------------
__global__ __launch_bounds__(1024) void wd_kernel(
    const float* __restrict__ part2, const float* __restrict__ xvecp,
    const float* __restrict__ Wq, const float* __restrict__ bq,
    const float* __restrict__ a_p,
    float* __restrict__ wd, float* __restrict__ awdT)
{
    __shared__ float S[K][C];
    __shared__ float xv[C + 1];
    __shared__ float T1s[C];
    const int t = threadIdx.x;          // t = k*64 + c
    const int c = t & 63;

    if (t < C + 1) {
        float s = 0.0f;
        #pragma unroll
        for (int ch = 0; ch < XCH; ++ch) s += xvecp[t * XCH + ch];
        xv[t] = s;
    }
    float s = 0.0f;
    #pragma unroll 8
    for (int b = 0; b < NB2R; ++b) s += part2[b * (K * C) + t];
    __syncthreads();

    if (t < C) {
        float t1 = bq[t] * xv[C];
        #pragma unroll 8
        for (int j = 0; j < C; ++j) t1 = fmaf(Wq[j * C + t], xv[j], t1);
        T1s[t] = t1;
    }
    __syncthreads();

    S[0][t] = s - T1s[c];
    __syncthreads();

    if (t < C) {
        float v[K];
        float m = -3.402823466e38f;
        #pragma unroll
        for (int k = 0; k < K; ++k) { v[k] = S[k][t]; m = fmaxf(m, v[k]); }
        float sum = 0.0f;
        #pragma unroll
        for (int k = 0; k < K; ++k) { v[k] = expf(v[k] - m); sum += v[k]; }
        const float r = 1.0f / sum;
        #pragma unroll
        for (int k = 0; k < K; ++k) {
            const float wv = v[k] * r;
            wd[t * K + k] = wv;
            awdT[k * C + t] = a_p[k] * wv;
        }
    }
}

// ---------------------------------------------------------------------------
// K3: w_e[n][k] = softmax_k( sum_c y[c][n] * wd[c][k] )   (separate kernel:
// low VGPR, high occupancy — merging with tab forced 256 VGPR, R10 lesson)
// ---------------------------------------------------------------------------
__global__ __launch_bounds__(256) void we_kernel(
    const float* __restrict__ y, const float* __restrict__ wd,
    float* __restrict__ we)
{
    __shared__ float wds[C][K];
    const int lane = threadIdx.x & 63;
    const int wave = threadIdx.x >> 6;
    for (int i = threadIdx.x; i < C * K; i += 256) wds[0][i] = wd[i];
    __syncthreads();

    const int n = (blockIdx.x * 4 + wave) * 64 + lane;
    float L[K];
    #pragma unroll
    for (int k = 0; k < K; ++k) L[k] = 0.0f;
    for (int c = 0; c < C; ++c) {
        const float yv = y[c * NPTS + n];
        float wa[K];
        ((float4*)wa)[0] = ((const float4*)&wds[c][0])[0];
        ((float4*)wa)[1] = ((const float4*)&wds[c][0])[1];
        ((float4*)wa)[2] = ((const float4*)&wds[c][0])[2];
        ((float4*)wa)[3] = ((const float4*)&wds[c][0])[3];
        #pragma unroll
        for (int k = 0; k < K; ++k) L[k] = fmaf(yv, wa[k], L[k]);
    }
    float m = L[0];
    #pragma unroll
    for (int k = 1; k < K; ++k) m = fmaxf(m, L[k]);
    float sum = 0.0f;
    #pragma unroll
    for (int k = 0; k < K; ++k) { L[k] = expf(L[k] - m); sum += L[k]; }
    const float r = 1.0f / sum;
    float* dst = we + (size_t)n * K;
    ((float4*)dst)[0] = make_float4(L[0]*r, L[1]*r, L[2]*r, L[3]*r);
    ((float4*)dst)[1] = make_float4(L[4]*r, L[5]*r, L[6]*r, L[7]*r);
    ((float4*)dst)[2] = make_float4(L[8]*r, L[9]*r, L[10]*r, L[11]*r);
    ((float4*)dst)[3] = make_float4(L[12]*r, L[13]*r, L[14]*r, L[15]*r);
}

// ---------------------------------------------------------------------------
// K3b: tabulate F_kc(t) (2-layer PWL map of scalar t) at t=i/NTAB, i=0..NTAB
// ---------------------------------------------------------------------------
__global__ __launch_bounds__(64) void tab_kernel(
    const float* __restrict__ awdT, const float* __restrict__ b_p,
    const float* __restrict__ Ww1, const float* __restrict__ bw1,
    const float* __restrict__ Ww2, const float* __restrict__ bw2,
    const float* __restrict__ gw1, const float* __restrict__ bw1b,
    const float* __restrict__ gw2, const float* __restrict__ bw2b,
    float* __restrict__ tab)
{
    const int lane = threadIdx.x;
    const int k  = blockIdx.y;
    const int i0 = blockIdx.x * 16;

    const float aw = awdT[k * C + lane];
    const float bp = b_p[k * C + lane];
    const float gs1 = gw1[lane] * BN_INV, bb1 = bw1b[lane], bw1c = bw1[lane];
    const float gs2 = gw2[lane] * BN_INV, bb2 = bw2b[lane], bw2c = bw2[lane];

    float w1c[C], w2c[C];
    #pragma unroll
    for (int c = 0; c < C; ++c) { w1c[c] = Ww1[c * C + lane]; w2c[c] = Ww2[c * C + lane]; }

    __shared__ float hs[16][C];

    #pragma unroll
    for (int r = 0; r < 16; ++r) {
        const float t = (float)(i0 + r) * (1.0f / NTAB);
        const float wv = fmaf(bp, t, aw);
        hs[r][lane] = fmaxf(fmaf(wv, gs1, bb1), 0.0f);
    }
    __syncthreads();

    float o[16];
    #pragma unroll
    for (int r = 0; r < 16; ++r) o[r] = bw1c;
    #pragma unroll
    for (int c4 = 0; c4 < 16; ++c4) {
        #pragma unroll
        for (int r = 0; r < 16; ++r) {
            const float4 hv = *(const float4*)&hs[r][c4 * 4];
            o[r] = fmaf(hv.x, w1c[c4 * 4 + 0], o[r]);
            o[r] = fmaf(hv.y, w1c[c4 * 4 + 1], o[r]);
            o[r] = fmaf(hv.z, w1c[c4 * 4 + 2], o[r]);
            o[r] = fmaf(hv.w, w1c[c4 * 4 + 3], o[r]);
        }
    }
    __syncthreads();
    #pragma unroll
    for (int r = 0; r < 16; ++r)
        hs[r][lane] = fmaxf(fmaf(o[r], gs2, bb2), 0.0f);
    __syncthreads();
    #pragma unroll
    for (int r = 0; r < 16; ++r) o[r] = bw2c;
    #pragma unroll
    for (int c4 = 0; c4 < 16; ++c4) {
        #pragma unroll
        for (int r = 0; r < 16; ++r) {
            const float4 hv = *(const float4*)&hs[r][c4 * 4];
            o[r] = fmaf(hv.x, w2c[c4 * 4 + 0], o[r]);
            o[r] = fmaf(hv.y, w2c[c4 * 4 + 1], o[r]);
            o[r] = fmaf(hv.z, w2c[c4 * 4 + 2], o[r]);
            o[r] = fmaf(hv.w, w2c[c4 * 4 + 3], o[r]);
        }
    }
    #pragma unroll
    for (int r = 0; r < 16; ++r) {
        const int i = i0 + r;
        if (i <= NTAB) tab[(k * (NTAB + 1) + i) * C + lane] = o[r];
    }
}

// ---------------------------------------------------------------------------
// K4 (hot): ONE point per wave (grid 8192 x 4 waves), lane = channel c.
// ---------------------------------------------------------------------------
__global__ __launch_bounds__(256, 5) void main4_kernel(
    const int* __restrict__ idx, const float4* __restrict__ pk,
    const __hip_bfloat16* __restrict__ yvb, const float* __restrict__ we,
    const float* __restrict__ tab, const float* __restrict__ d_p,
    const float* __restrict__ Wa1, const float* __restrict__ ba1,
    const float* __restrict__ ga, const float* __restrict__ bna,
    const float* __restrict__ Wa2, const float* __restrict__ ba2,
    const float* __restrict__ Wp1, const float* __restrict__ bp1,
    const float* __restrict__ gp, const float* __restrict__ bnp,
    const float* __restrict__ Wp2, const float* __restrict__ bp2,
    float* __restrict__ out)
{
    const int lane = threadIdx.x & 63;
    const int wv = __builtin_amdgcn_readfirstlane(threadIdx.x >> 6);
    const int n = blockIdx.x * 4 + wv;                 // uniform point id

    __shared__ float geo[4][K][8];
    __shared__ float prm[36];

    if (threadIdx.x < 36) {
        const int t = threadIdx.x;
        float v;
        if (t < 9)       v = Wa1[t];
        else if (t < 12) v = ba1[t - 9];
        else if (t < 21) v = Wp1[t - 12];
        else if (t < 24) v = bp1[t - 21];
        else if (t < 27) v = ga[t - 24];
        else if (t < 30) v = bna[t - 27];
        else if (t < 33) v = gp[t - 30];
        else             v = bnp[t - 33];
        prm[t] = v;
    }
    __syncthreads();

    // ---- uniform loads (scalar path) ----
    const int4* ir = (const int4*)(idx + (size_t)n * K);
    const int4 i0 = ir[0], i1 = ir[1], i2 = ir[2], i3 = ir[3];
    const int ids[K] = { i0.x, i0.y, i0.z, i0.w, i1.x, i1.y, i1.z, i1.w,
                         i2.x, i2.y, i2.z, i2.w, i3.x, i3.y, i3.z, i3.w };
    const float4 self = pk[n];
    const float4 wv0 = ((const float4*)(we + (size_t)n * K))[0];
    const float4 wv1 = ((const float4*)(we + (size_t)n * K))[1];
    const float4 wv2 = ((const float4*)(we + (size_t)n * K))[2];
    const float4 wv3 = ((const float4*)(we + (size_t)n * K))[3];
    const float wearr[K] = { wv0.x, wv0.y, wv0.z, wv0.w, wv1.x, wv1.y, wv1.z, wv1.w,
                             wv2.x, wv2.y, wv2.z, wv2.w, wv3.x, wv3.y, wv3.z, wv3.w };

    // ---- per-lane gathers: yv rows (saddr + lane*2) ----
    const ushort* __restrict__ yvu_base = (const ushort*)yvb;
    ushort yvu[K];
    #pragma unroll
    for (int k = 0; k < K; ++k)
        yvu[k] = yvu_base[(size_t)ids[k] * C + lane];

    // ---- geometry (lanes compute k = lane&15; lanes<16 write LDS) ----
    {
        const int idv = (idx + (size_t)n * K)[lane & 15];   // per-lane
        const float4 nb = pk[idv];
        const float px = nb.x - self.x;
        const float py = nb.y - self.y;
        const float pz = nb.z - self.z;
        const float ed  = sqrtf(px * px + py * py + pz * pz);
        const float exy = sqrtf(px * px + py * py);
        const float cose = safediv_n2n(exy, ed);
        const float cosa = safediv_n2n(py, exy);
        float gv[6];
        #pragma unroll
        for (int d = 0; d < 3; ++d) {
            const float a = ed * prm[d] + cosa * prm[3 + d] + cose * prm[6 + d] + prm[9 + d];
            gv[d] = fmaxf(a * (prm[24 + d] * BN_INV) + prm[27 + d], 0.0f);
            const float p = px * prm[12 + d] + py * prm[15 + d] + pz * prm[18 + d] + prm[21 + d];
            gv[3 + d] = fmaxf(p * (prm[30 + d] * BN_INV) + prm[33 + d], 0.0f);
        }
        if (lane < K) {
            float* g = &geo[wv][lane][0];
            g[1] = gv[0]; g[2] = gv[1]; g[3] = gv[2];
            g[4] = gv[3]; g[5] = gv[4]; g[6] = gv[5];
        }
    }

    // ---- w2[k] via table lerp, two batches of 8 (register diet) ----
    float w2[K];
    #pragma unroll
    for (int h = 0; h < 2; ++h) {
        float tv0[8], tv1[8], fr[8];
        #pragma unroll
        for (int j = 0; j < 8; ++j) {
            const int k = h * 8 + j;
            const float u = wearr[k] * (float)NTAB;
            int ic = (int)u;
            ic = (ic < 0) ? 0 : (ic > NTAB - 1 ? NTAB - 1 : ic);
            fr[j] = u - (float)ic;
            const float* tp = tab + ((size_t)(k * (NTAB + 1) + ic) << 6) + lane;
            tv0[j] = tp[0];
            tv1[j] = tp[C];
        }
        #pragma unroll
        for (int j = 0; j < 8; ++j)
            w2[h * 8 + j] = fmaf(fr[j], tv1[j] - tv0[j], tv0[j]);
    }

    // ---- softmax over k ----
    float m = w2[0];
    #pragma unroll
    for (int k = 1; k < K; ++k) m = fmaxf(m, w2[k]);
    float sum = 0.0f;
    #pragma unroll
    for (int k = 0; k < K; ++k) { w2[k] = __expf(w2[k] - m); sum += w2[k]; }
    const float r = 1.0f / sum;

    // ---- per-lane params ----
    const float ba2c = ba2[lane], bp2c = bp2[lane];
    float wa2c[3], wp2c[3];
    #pragma unroll
    for (int d = 0; d < 3; ++d) { wa2c[d] = Wa2[d * C + lane]; wp2c[d] = Wp2[d * C + lane]; }

    // ---- epilogue: out = sum_k (y_v_gather + p_r) * w ----
    float acc = 0.0f;
    #pragma unroll
    for (int k = 0; k < K; ++k) {
        const float4 g0 = *(const float4*)&geo[wv][k][0];
        const float4 g1 = *(const float4*)&geo[wv][k][4];
        const float afc = fmaf(g0.y, wa2c[0], fmaf(g0.z, wa2c[1], fmaf(g0.w, wa2c[2], ba2c)));
        float prc = fmaf(g1.x, wp2c[0], fmaf(g1.y, wp2c[1], fmaf(g1.z, wp2c[2], bp2c)));
        prc = fmaf(d_p[k * C + lane], afc, prc);
        acc = fmaf(bf16f(yvu[k]) + prc, w2[k] * r, acc);
    }
    out[(size_t)n * C + lane] = acc;
}

// ---------------------------------------------------------------------------
extern "C" void kernel_launch(void* const* d_in, const int* in_sizes, int n_in,
                              void* d_out, int out_size, void* d_ws, size_t ws_size,
                              hipStream_t stream)
{
    (void)in_sizes; (void)n_in; (void)out_size; (void)ws_size;
    const float* x     = (const float*)d_in[0];
    const float* y     = (const float*)d_in[1];
    const float* y_xyz = (const float*)d_in[2];
    const int*   idx   = (const int*)d_in[3];
    const float* Wq = (const float*)d_in[4];  const float* bq = (const float*)d_in[5];
    const float* Wk = (const float*)d_in[6];  const float* bk = (const float*)d_in[7];
    const float* Wv = (const float*)d_in[8];  const float* bv = (const float*)d_in[9];
    const float* Wu = (const float*)d_in[10]; const float* bu = (const float*)d_in[11];
    const float* gu = (const float*)d_in[12]; const float* bnu = (const float*)d_in[13];
    const float* Wp1 = (const float*)d_in[14]; const float* bp1 = (const float*)d_in[15];
    const float* gp  = (const float*)d_in[16]; const float* bnp = (const float*)d_in[17];
    const float* Wp2 = (const float*)d_in[18]; const float* bp2 = (const float*)d_in[19];
    const float* Wa1 = (const float*)d_in[20]; const float* ba1 = (const float*)d_in[21];
    const float* ga  = (const float*)d_in[22]; const float* bna = (const float*)d_in[23];
    const float* Wa2 = (const float*)d_in[24]; const float* ba2 = (const float*)d_in[25];
    const float* gw1 = (const float*)d_in[26]; const float* bw1b = (const float*)d_in[27];
    const float* Ww1 = (const float*)d_in[28]; const float* bw1 = (const float*)d_in[29];
    const float* gw2 = (const float*)d_in[30]; const float* bw2b = (const float*)d_in[31];
    const float* Ww2 = (const float*)d_in[32]; const float* bw2 = (const float*)d_in[33];
    const float* a_p = (const float*)d_in[34];
    const float* b_p = (const float*)d_in[35];
    const float* d_p = (const float*)d_in[36];
    float* out = (float*)d_out;

    float* ws = (float*)d_ws;
    // layout (float offsets), compacted:
    float* we    = ws;                                   // 524288
    float* tab   = ws + 524288;                          // 525312 -> 1049600
    __hip_bfloat16* ykb = (__hip_bfloat16*)(ws + 1049600);   // 4MB -> +1048576
    __hip_bfloat16* yvb = (__hip_bfloat16*)(ws + 2098176);   // 4MB -> +1048576
    float4* pk   = (float4*)(ws + 3146752);              // 131072 -> 3277824
    float* xu    = ws + 3277824;                         // 32768 -> 3310592
    float* partG = ws + 3310592;                         // 2048*1024 -> 5407744
    float* part2 = ws + 5407744;                         // 65536 -> 5473280
    float* wd    = ws + 5473280;                         // 1024
    float* awdT  = ws + 5474304;                         // 1024
    float* xvecp = ws + 5475328;                         // 520

    prep_kernel<<<dim3(NPTS / 64, 3), 256, 0, stream>>>(
        x, y, y_xyz, Wk, bk, Wv, bv, Wu, bu, gu, bnu, ykb, yvb, xu, pk);
    sredx_kernel<<<NB2 + (C + 1) * XCH, 256, 0, stream>>>(
        ykb, x, xu, idx, partG, xvecp);
    sred2_kernel<<<NB2R, 1024, 0, stream>>>(partG, part2);
    wd_kernel<<<1, 1024, 0, stream>>>(part2, xvecp, Wq, bq, a_p, wd, awdT);
    we_kernel<<<NPTS / 256, 256, 0, stream>>>(y, wd, we);
    tab_kernel<<<dim3(33, 16), 64, 0, stream>>>(awdT, b_p, Ww1, bw1, Ww2, bw2,
                                                gw1, bw1b, gw2, bw2b, tab);
    main4_kernel<<<NPTS / 4, 256, 0, stream>>>(idx, pk, yvb, we, tab, d_p,
        Wa1, ba1, ga, bna, Wa2, ba2, Wp1, bp1, gp, bnp, Wp2, bp2, out);
}